// Round 10
// baseline (434.280 us; speedup 1.0000x reference)
//
#include <hip/hip_runtime.h>
#include <math.h>

// Problem constants (from reference setup_inputs)
constexpr int NV  = 16000;   // voxels
constexpr int P   = 32;      // points per voxel
constexpr int CIN = 10;      // input channels
constexpr int CV  = 64;      // voxel feature channels
constexpr int NB  = 16000;   // BEV cells
constexpr int BEV_H = 496, BEV_W = 432;
constexpr int HW = BEV_H * BEV_W;  // 214272
constexpr float EPS = 1e-5f;

typedef __attribute__((ext_vector_type(8))) short short8_t;  // 8 bf16 (4 VGPR)
typedef __attribute__((ext_vector_type(4))) short short4_t;  // 4 bf16
typedef __attribute__((ext_vector_type(4))) float fx4;       // MFMA C/D frag
typedef __attribute__((ext_vector_type(2))) float f32x2;     // packed f32 pair

// 8-op mish: tanh(softplus(x)) = 1 - 2/((1+e^x)^2+1)  ->  mish = x - 2x/d
__device__ __forceinline__ float mish(float x) {
  float e = __expf(fminf(x, 15.f));
  float u = 1.f + e;
  float d = fmaf(u, u, 1.f);
  float r = __builtin_amdgcn_rcpf(d);
  return fmaf(-2.f * x, r, x);
}

// RNE f32->bf16 (cold paths: weight packing)
__device__ __forceinline__ short f2bf(float f) {
  unsigned u = __builtin_bit_cast(unsigned, f);
  u += 0x7FFF + ((u >> 16) & 1);
  return (short)(u >> 16);
}
__device__ __forceinline__ float bf2f(short s) {
  unsigned u = ((unsigned)(unsigned short)s) << 16;
  return __builtin_bit_cast(float, u);
}
__device__ __forceinline__ short8_t pack8(const float* t) {
  short8_t s;
#pragma unroll
  for (int j = 0; j < 8; ++j) s[j] = f2bf(t[j]);
  return s;
}

// hot-path pack: round-half-up + v_perm pair  (low16 = bf16(a), high16 = bf16(b))
__device__ __forceinline__ unsigned bfpair(float a, float b) {
  unsigned au = __builtin_bit_cast(unsigned, a) + 0x8000u;
  unsigned bu = __builtin_bit_cast(unsigned, b) + 0x8000u;
  return __builtin_amdgcn_perm(bu, au, 0x07060302u);
}
// Dekker-style split pair: returns hi-pack, writes exact lo residuals
__device__ __forceinline__ unsigned hipack(float a, float b, float& la, float& lb) {
  unsigned ua = (__builtin_bit_cast(unsigned, a) + 0x8000u) & 0xFFFF0000u;
  unsigned ub = (__builtin_bit_cast(unsigned, b) + 0x8000u) & 0xFFFF0000u;
  la = a - __builtin_bit_cast(float, ua);
  lb = b - __builtin_bit_cast(float, ub);
  return __builtin_amdgcn_perm(ub, ua, 0x07060302u);
}

// ---------------------------------------------------------------------------
// Prologue: pack bfe weights to bf16 (hi only for bfe12; hi/lo for bfe3).
// ---------------------------------------------------------------------------
__global__ __launch_bounds__(256) void pack_weights_kernel(
    const float* __restrict__ W1, const float* __restrict__ W2a,
    const float* __restrict__ W2b, const float* __restrict__ W3,
    short* __restrict__ w1h,
    short* __restrict__ w2ah,
    short* __restrict__ w2bh,
    short* __restrict__ w3h, short* __restrict__ w3l)
{
  int i = blockIdx.x * 256 + threadIdx.x;
  if (i < 65536) {
    w1h[i] = f2bf(W1[i]);
  } else if (i < 81920) {
    int j = i - 65536;
    int g = j >> 10, o = (j >> 6) & 15, c = j & 63;
    float v = (o < 8) ? W2a[(g * 8 + o) * 64 + c] : 0.f;
    w2ah[j] = f2bf(v);
  } else if (i < 90112) {
    int k = i - 81920;
    int g = k >> 9, o = (k >> 5) & 15, c = k & 31;
    float v = (o < 8) ? W2b[(g * 8 + o) * 32 + c] : 0.f;
    w2bh[k] = f2bf(v);
  } else if (i < 106496) {
    int j = i - 90112;
    float v = W3[j];
    short h = f2bf(v);
    w3h[j] = h; w3l[j] = f2bf(v - bf2f(h));
  }
}

// ---------------------------------------------------------------------------
// VFE v5 (unchanged r9): bf16 voxelwise output.
// ---------------------------------------------------------------------------
__global__ __launch_bounds__(256, 4) void vfe_mfma5_kernel(
    const float* __restrict__ voxels, const float* __restrict__ vmask,
    const float* __restrict__ W1, const float* __restrict__ g1, const float* __restrict__ b1,
    const float* __restrict__ W2, const float* __restrict__ g2, const float* __restrict__ b2,
    const float* __restrict__ W3, const float* __restrict__ g3, const float* __restrict__ b3,
    const float* __restrict__ W4, const float* __restrict__ g4, const float* __restrict__ b4,
    unsigned short* __restrict__ voxelwise)
{
  __shared__ short wlds[28 * 512];
  __shared__ short actb[4][16 * 72];
  __shared__ float gblds[512];

  const int tid  = threadIdx.x;
  const int lane = tid & 63;
  const int w    = tid >> 6;
  const int p    = lane & 15;
  const int q    = lane >> 4;
  const int gw   = blockIdx.x * 4 + w;

  for (int k = tid; k < 512; k += 256) {
    int region = k >> 6, off = k & 63;
    const float* src =
        region == 0 ? g1 : region == 1 ? b1 :
        region == 2 ? g2 : region == 3 ? b2 :
        region == 4 ? g3 : region == 5 ? b3 :
        region == 6 ? g4 : b4;
    gblds[k] = src[off];
  }
  for (int s = w; s < 28; s += 4) {
    float t[8];
    if (s < 4) {
      const int f = s;
#pragma unroll
      for (int j = 0; j < 8; ++j) {
        int c = 8 * q + j;
        t[j] = (c < CIN) ? W1[(p + 16 * f) * CIN + c] : 0.f;
      }
    } else {
      const int l = (s - 4) >> 3, rem = (s - 4) & 7, ch = rem >> 2, f = rem & 3;
      const float* Wl = (l == 0) ? W2 : (l == 1) ? W3 : W4;
      const float* src = Wl + (p + 16 * f) * CV + 32 * ch + 8 * q;
#pragma unroll
      for (int j = 0; j < 8; ++j) t[j] = src[j];
    }
    *(short8_t*)&wlds[s * 512 + lane * 8] = pack8(t);
  }
  __syncthreads();

  short* mybuf = &actb[w][0];
  const fx4 zacc = {0.f, 0.f, 0.f, 0.f};
  const int srcLane = ((lane >> 2) & 3) * 16 + (((lane >> 4) & 3) << 2) + (lane & 3);

  for (int i = 0; i < 4; ++i) {
    const int v = gw * 4 + i;
    float chmax0 = 0.f, vmaxv = 0.f;

    for (int h = 0; h < 2; ++h) {
      const int ptbase = v * 32 + h * 16;
      const float m = vmask[ptbase + p];
      float x2r[16];
      float cur[16];

      // ---- layer 1 ----
      {
        const float* xrow = voxels + (size_t)(ptbase + p) * CIN;
        float t[8] = {0.f, 0.f, 0.f, 0.f, 0.f, 0.f, 0.f, 0.f};
        if (q == 0) {
          float2 a = *(const float2*)(xrow + 0);
          float2 b = *(const float2*)(xrow + 2);
          float2 c = *(const float2*)(xrow + 4);
          float2 d = *(const float2*)(xrow + 6);
          t[0] = a.x; t[1] = a.y; t[2] = b.x; t[3] = b.y;
          t[4] = c.x; t[5] = c.y; t[6] = d.x; t[7] = d.y;
        } else if (q == 1) {
          float2 a = *(const float2*)(xrow + 8);
          t[0] = a.x; t[1] = a.y;
        }
        uint4 bu = make_uint4(bfpair(t[0], t[1]), bfpair(t[2], t[3]),
                              bfpair(t[4], t[5]), bfpair(t[6], t[7]));
        short8_t bfrag = __builtin_bit_cast(short8_t, bu);
        fx4 acc[4];
#pragma unroll
        for (int f = 0; f < 4; ++f) {
          short8_t af = *(short8_t*)&wlds[f * 512 + lane * 8];
          acc[f] = __builtin_amdgcn_mfma_f32_16x16x32_bf16(af, bfrag, zacc, 0, 0, 0);
        }
        f32x2 s1v = {0.f, 0.f}, s2v = {0.f, 0.f};
#pragma unroll
        for (int f = 0; f < 4; ++f) {
          f32x2 a01 = __builtin_shufflevector(acc[f], acc[f], 0, 1);
          f32x2 a23 = __builtin_shufflevector(acc[f], acc[f], 2, 3);
          s1v = s1v + a01 + a23;
          s2v = __builtin_elementwise_fma(a01, a01, s2v);
          s2v = __builtin_elementwise_fma(a23, a23, s2v);
        }
        float s1 = s1v[0] + s1v[1], s2 = s2v[0] + s2v[1];
        s1 += __shfl_xor(s1, 16); s1 += __shfl_xor(s1, 32);
        s2 += __shfl_xor(s2, 16); s2 += __shfl_xor(s2, 32);
        float mean = s1 * (1.f / 64.f);
        float rstd = rsqrtf(fmaf(-mean, mean, s2 * (1.f / 64.f)) + EPS);
        float ms = -mean * rstd;
#pragma unroll
        for (int f = 0; f < 4; ++f) {
          float4 gv = *(const float4*)&gblds[16 * f + 4 * q];
          float4 bv = *(const float4*)&gblds[64 + 16 * f + 4 * q];
          float go[4] = {gv.x, gv.y, gv.z, gv.w};
          float bo[4] = {bv.x, bv.y, bv.z, bv.w};
          float o[4];
#pragma unroll
          for (int r = 0; r < 4; ++r)
            o[r] = mish(fmaf(fmaf(acc[f][r], rstd, ms), go[r], bo[r]));
          *(uint2*)&mybuf[p * 72 + 4 * q + 16 * f] =
              make_uint2(bfpair(o[0], o[1]), bfpair(o[2], o[3]));
        }
      }

      // ---- layers 2..4 ----
#pragma unroll 1
      for (int l = 0; l < 3; ++l) {
        short8_t bf0 = *(short8_t*)&mybuf[p * 72 + 8 * q];
        short8_t bf1 = *(short8_t*)&mybuf[p * 72 + 8 * q + 32];
        fx4 acc[4];
#pragma unroll
        for (int f = 0; f < 4; ++f) {
          short8_t a0 = *(short8_t*)&wlds[(4 + l * 8 + f) * 512 + lane * 8];
          short8_t a1 = *(short8_t*)&wlds[(4 + l * 8 + 4 + f) * 512 + lane * 8];
          fx4 a = __builtin_amdgcn_mfma_f32_16x16x32_bf16(a0, bf0, zacc, 0, 0, 0);
          acc[f] = __builtin_amdgcn_mfma_f32_16x16x32_bf16(a1, bf1, a, 0, 0, 0);
        }
        f32x2 s1v = {0.f, 0.f}, s2v = {0.f, 0.f};
#pragma unroll
        for (int f = 0; f < 4; ++f) {
          f32x2 a01 = __builtin_shufflevector(acc[f], acc[f], 0, 1);
          f32x2 a23 = __builtin_shufflevector(acc[f], acc[f], 2, 3);
          s1v = s1v + a01 + a23;
          s2v = __builtin_elementwise_fma(a01, a01, s2v);
          s2v = __builtin_elementwise_fma(a23, a23, s2v);
        }
        float s1 = s1v[0] + s1v[1], s2 = s2v[0] + s2v[1];
        s1 += __shfl_xor(s1, 16); s1 += __shfl_xor(s1, 32);
        s2 += __shfl_xor(s2, 16); s2 += __shfl_xor(s2, 32);
        float mean = s1 * (1.f / 64.f);
        float rstd = rsqrtf(fmaf(-mean, mean, s2 * (1.f / 64.f)) + EPS);
        float ms = -mean * rstd;
        const int gbbase = (l + 1) * 128;
#pragma unroll
        for (int f = 0; f < 4; ++f) {
          float4 gv = *(const float4*)&gblds[gbbase + 16 * f + 4 * q];
          float4 bv = *(const float4*)&gblds[gbbase + 64 + 16 * f + 4 * q];
          float go[4] = {gv.x, gv.y, gv.z, gv.w};
          float bo[4] = {bv.x, bv.y, bv.z, bv.w};
          if (l == 0) {
            float o[4];
#pragma unroll
            for (int r = 0; r < 4; ++r) {
              o[r] = mish(fmaf(fmaf(acc[f][r], rstd, ms), go[r], bo[r])) * m;
              x2r[f * 4 + r] = o[r];
            }
            *(uint2*)&mybuf[p * 72 + 4 * q + 16 * f] =
                make_uint2(bfpair(o[0], o[1]), bfpair(o[2], o[3]));
          } else if (l == 1) {
            float o[4];
#pragma unroll
            for (int r = 0; r < 4; ++r)
              o[r] = mish(fmaf(fmaf(acc[f][r], rstd, ms), go[r], bo[r]));
            *(uint2*)&mybuf[p * 72 + 4 * q + 16 * f] =
                make_uint2(bfpair(o[0], o[1]), bfpair(o[2], o[3]));
          } else {
#pragma unroll
            for (int r = 0; r < 4; ++r) {
              float t1 = fmaf(fmaf(acc[f][r], rstd, ms), go[r], bo[r]);
              cur[f * 4 + r] = fmaf(mish(t1), m, x2r[f * 4 + r]);
            }
          }
        }
      }

      // ---- reduce-scatter max over 16 points; lane p keeps value j=p ----
#pragma unroll
      for (int t = 0; t < 8; ++t) {
        float send = (lane & 8) ? cur[t] : cur[t + 8];
        float got  = __shfl_xor(send, 8);
        float mine = (lane & 8) ? cur[t + 8] : cur[t];
        cur[t] = fmaxf(mine, got);
      }
#pragma unroll
      for (int t = 0; t < 4; ++t) {
        float send = (lane & 4) ? cur[t] : cur[t + 4];
        float got  = __shfl_xor(send, 4);
        float mine = (lane & 4) ? cur[t + 4] : cur[t];
        cur[t] = fmaxf(mine, got);
      }
#pragma unroll
      for (int t = 0; t < 2; ++t) {
        float send = (lane & 2) ? cur[t] : cur[t + 2];
        float got  = __shfl_xor(send, 2);
        float mine = (lane & 2) ? cur[t + 2] : cur[t];
        cur[t] = fmaxf(mine, got);
      }
      {
        float send = (lane & 1) ? cur[0] : cur[1];
        float got  = __shfl_xor(send, 1);
        float mine = (lane & 1) ? cur[1] : cur[0];
        cur[0] = fmaxf(mine, got);
      }
      float hm = __shfl(cur[0], srcLane);
      if (h == 0) chmax0 = hm; else vmaxv = fmaxf(chmax0, hm);
    }
    unsigned uv = __builtin_bit_cast(unsigned, vmaxv) + 0x8000u;
    voxelwise[v * 64 + lane] = (unsigned short)(uv >> 16);
  }
}

// ---------------------------------------------------------------------------
// Kernel 2 v5: software-pipelined gather. Stage j+1's 8 global loads are
// issued right after stage j's xbuf-ready barrier and consumed (transpose +
// vmcnt wait) at the TOP of iteration j+1, before the barriers — so their
// latency hides behind stage j's compute. Numerics identical to v4.
// ---------------------------------------------------------------------------
constexpr int XS_CH   = 72;
constexpr int XS_CELL = 16 * 72 + 16;
constexpr int ACT_OFF = 8 * XS_CELL;
constexpr int ACT_WS  = 16 * 72;
constexpr int H2_OFF  = ACT_OFF + 4 * ACT_WS;
constexpr int H2_WS   = 16 * 40;
constexpr int X17_OFF = H2_OFF + 4 * H2_WS;          // 16512 shorts (16B-aligned)
constexpr int SMEM_SHORTS = X17_OFF + 8 * 132 * 2;   // + x17lds (8*132 floats)

__device__ __forceinline__ uint2 gather_transpose(uint2 u2, int bit0, int bit1) {
  float a0 = __builtin_bit_cast(float, u2.x << 16);
  float a1 = __builtin_bit_cast(float, u2.x & 0xFFFF0000u);
  float a2 = __builtin_bit_cast(float, u2.y << 16);
  float a3 = __builtin_bit_cast(float, u2.y & 0xFFFF0000u);
  float gv0 = bit0 ? a0 : a1, gv1 = bit0 ? a2 : a3;
  float r0 = __shfl_xor(gv0, 4), r1 = __shfl_xor(gv1, 4);
  float c0 = bit0 ? r0 : a0, c1 = bit0 ? a1 : r0;
  float c2 = bit0 ? r1 : a2, c3 = bit0 ? a3 : r1;
  float h0 = bit1 ? c0 : c2, h1 = bit1 ? c1 : c3;
  float s0 = __shfl_xor(h0, 8), s1 = __shfl_xor(h1, 8);
  float d0 = bit1 ? s0 : c0, d1 = bit1 ? s1 : c1;
  float d2 = bit1 ? c2 : s0, d3 = bit1 ? c3 : s1;
  // bfpair exact here (inputs already bf16 bit patterns)
  return make_uint2(bfpair(d0, d1), bfpair(d2, d3));
}

__global__ __launch_bounds__(256, 4) void bfe12_mfma5_kernel(
    const unsigned short* __restrict__ voxelwise, const int* __restrict__ bevsidx,
    const float* __restrict__ bevmask,
    const short* __restrict__ w1h,
    const float* __restrict__ g1, const float* __restrict__ b1,
    const short* __restrict__ w2ah,
    const float* __restrict__ g2a, const float* __restrict__ b2a,
    const short* __restrict__ w2bh,
    const float* __restrict__ g2b, const float* __restrict__ b2b,
    float* __restrict__ x17buf)
{
  extern __shared__ short sm[];
  float* x17lds = (float*)&sm[X17_OFF];

  const int tid  = threadIdx.x;
  const int lane = tid & 63;
  const int w    = tid >> 6;
  const int r15  = lane & 15;
  const int q    = lane >> 4;
  const int cellbase = blockIdx.x * 8;

  const int chq   = lane & 3;
  const int v_loc = (lane >> 2) & 3;
  const int vblk  = lane >> 4;
  const int bit0  = v_loc & 1, bit1 = v_loc >> 1;

  int idxr[2][4];
#pragma unroll
  for (int cc = 0; cc < 2; ++cc)
#pragma unroll
    for (int vb = 0; vb < 4; ++vb) {
      int v = 16 * vb + 4 * vblk + v_loc;
      idxr[cc][vb] = bevsidx[(cellbase + 2 * w + cc) * 64 + v];
    }

  {
    short* zh = &sm[H2_OFF + w * H2_WS];
    for (int i = lane; i < 320; i += 64) zh[320 + i] = 0;
  }

  const fx4 zacc = {0.f, 0.f, 0.f, 0.f};
  short* acth = &sm[ACT_OFF + w * ACT_WS];
  short* h2h  = &sm[H2_OFF + w * H2_WS];

  // ---- prologue: issue stage-0 gather loads ----
  uint2 pre[2][4];
#pragma unroll
  for (int cc = 0; cc < 2; ++cc)
#pragma unroll
    for (int vb = 0; vb < 4; ++vb)
      pre[cc][vb] = *(const uint2*)(voxelwise + (size_t)idxr[cc][vb] * 64 + 4 * chq);

#pragma unroll 1
  for (int j = 0; j < 4; ++j) {
    const int g = 4 * j + w;

    // consume prefetched loads (vmcnt wait lands here, outside barriers)
    uint2 packed[2][4];
#pragma unroll
    for (int cc = 0; cc < 2; ++cc)
#pragma unroll
      for (int vb = 0; vb < 4; ++vb)
        packed[cc][vb] = gather_transpose(pre[cc][vb], bit0, bit1);

    __syncthreads();   // prior stage's xbuf reads complete

#pragma unroll
    for (int cc = 0; cc < 2; ++cc)
#pragma unroll
      for (int vb = 0; vb < 4; ++vb) {
        int addr = (2 * w + cc) * XS_CELL + (4 * chq + v_loc) * XS_CH + 16 * vb + 4 * vblk;
        *(uint2*)&sm[addr] = packed[cc][vb];
      }

    __syncthreads();   // xbuf ready

    // ---- fire next stage's gather; latency hides behind this stage ----
    if (j < 3) {
#pragma unroll
      for (int cc = 0; cc < 2; ++cc)
#pragma unroll
        for (int vb = 0; vb < 4; ++vb)
          pre[cc][vb] = *(const uint2*)(voxelwise + (size_t)idxr[cc][vb] * 64 +
                                        (j + 1) * 16 + 4 * chq);
    }

    short8_t W1f[2][4];
#pragma unroll
    for (int c = 0; c < 2; ++c)
#pragma unroll
      for (int f = 0; f < 4; ++f) {
        int off = (g * 64 + r15 + 16 * f) * 64 + 32 * c + 8 * q;
        W1f[c][f] = *(const short8_t*)&w1h[off];
      }
    short8_t W2af[2];
#pragma unroll
    for (int c = 0; c < 2; ++c) {
      int off = (g * 16 + r15) * 64 + 32 * c + 8 * q;
      W2af[c] = *(const short8_t*)&w2ah[off];
    }
    short8_t W2bf;
    {
      int off = (g * 16 + r15) * 32 + 8 * q;
      W2bf = *(const short8_t*)&w2bh[off];
    }

#pragma unroll 1
    for (int t = 0; t < 2; ++t) {
      const int cl = r15 >> 2, p = r15 & 3;
      const int cell_loc = 4 * t + cl;
      const float bm = bevmask[cellbase + cell_loc];

      int xaddr = cell_loc * XS_CELL + (4 * w + p) * XS_CH;
      short8_t x0 = *(short8_t*)&sm[xaddr + 8 * q];
      short8_t x1 = *(short8_t*)&sm[xaddr + 32 + 8 * q];

      fx4 acc[4];
#pragma unroll
      for (int f = 0; f < 4; ++f) {
        fx4 a = __builtin_amdgcn_mfma_f32_16x16x32_bf16(W1f[0][f], x0, zacc, 0, 0, 0);
        acc[f] = __builtin_amdgcn_mfma_f32_16x16x32_bf16(W1f[1][f], x1, a, 0, 0, 0);
      }

      f32x2 s1v = {0.f, 0.f}, s2v = {0.f, 0.f};
#pragma unroll
      for (int f = 0; f < 4; ++f) {
        f32x2 a01 = __builtin_shufflevector(acc[f], acc[f], 0, 1);
        f32x2 a23 = __builtin_shufflevector(acc[f], acc[f], 2, 3);
        s1v = s1v + a01 + a23;
        s2v = __builtin_elementwise_fma(a01, a01, s2v);
        s2v = __builtin_elementwise_fma(a23, a23, s2v);
      }
      float s1 = s1v[0] + s1v[1], s2 = s2v[0] + s2v[1];
      s1 += __shfl_xor(s1, 16); s1 += __shfl_xor(s1, 32);
      s2 += __shfl_xor(s2, 16); s2 += __shfl_xor(s2, 32);
      float mean = s1 * (1.f / 64.f);
      float rstd = rsqrtf(fmaf(-mean, mean, s2 * (1.f / 64.f)) + EPS);
      float ms = -mean * rstd;

#pragma unroll
      for (int f = 0; f < 4; ++f) {
        float4 gv = *(const float4*)(g1 + g * 64 + 16 * f + 4 * q);
        float4 bv = *(const float4*)(b1 + g * 64 + 16 * f + 4 * q);
        float go[4] = {gv.x, gv.y, gv.z, gv.w};
        float bo[4] = {bv.x, bv.y, bv.z, bv.w};
        float o[4];
#pragma unroll
        for (int r = 0; r < 4; ++r)
          o[r] = mish(fmaf(fmaf(acc[f][r], rstd, ms), go[r], bo[r])) * bm;
        *(uint2*)&acth[r15 * 72 + 16 * f + 4 * q] =
            make_uint2(bfpair(o[0], o[1]), bfpair(o[2], o[3]));
      }

      short8_t a0 = *(short8_t*)&acth[r15 * 72 + 8 * q];
      short8_t a1 = *(short8_t*)&acth[r15 * 72 + 32 + 8 * q];
      fx4 a2 = __builtin_amdgcn_mfma_f32_16x16x32_bf16(W2af[0], a0, zacc, 0, 0, 0);
      a2 = __builtin_amdgcn_mfma_f32_16x16x32_bf16(W2af[1], a1, a2, 0, 0, 0);

      float sa = a2[0] + a2[1] + a2[2] + a2[3];
      float sb = fmaf(a2[0], a2[0], fmaf(a2[1], a2[1], fmaf(a2[2], a2[2], a2[3] * a2[3])));
      sa += __shfl_xor(sa, 16); sb += __shfl_xor(sb, 16);
      if (q < 2) {
        float mean2 = sa * 0.125f;
        float rstd2 = rsqrtf(fmaf(-mean2, mean2, sb * 0.125f) + EPS);
        float ms2 = -mean2 * rstd2;
        float4 gv = *(const float4*)(g2a + g * 8 + 4 * q);
        float4 bv = *(const float4*)(b2a + g * 8 + 4 * q);
        float go[4] = {gv.x, gv.y, gv.z, gv.w};
        float bo[4] = {bv.x, bv.y, bv.z, bv.w};
        float o[4];
#pragma unroll
        for (int r = 0; r < 4; ++r)
          o[r] = mish(fmaf(fmaf(a2[r], rstd2, ms2), go[r], bo[r]));
        *(uint2*)&h2h[cell_loc * 40 + p * 8 + 4 * q] =
            make_uint2(bfpair(o[0], o[1]), bfpair(o[2], o[3]));
      }
    }

    // ---- bfe2b -> x17 staged in LDS ----
    {
      short8_t bh = *(short8_t*)&h2h[r15 * 40 + 8 * q];
      fx4 a3 = __builtin_amdgcn_mfma_f32_16x16x32_bf16(W2bf, bh, zacc, 0, 0, 0);

      float sa = a3[0] + a3[1] + a3[2] + a3[3];
      float sb = fmaf(a3[0], a3[0], fmaf(a3[1], a3[1], fmaf(a3[2], a3[2], a3[3] * a3[3])));
      sa += __shfl_xor(sa, 16); sb += __shfl_xor(sb, 16);
      if (q < 2 && r15 < 8) {
        float mean3 = sa * 0.125f;
        float rstd3 = rsqrtf(fmaf(-mean3, mean3, sb * 0.125f) + EPS);
        float ms3 = -mean3 * rstd3;
        float4 gv = *(const float4*)(g2b + g * 8 + 4 * q);
        float4 bv = *(const float4*)(b2b + g * 8 + 4 * q);
        float go[4] = {gv.x, gv.y, gv.z, gv.w};
        float bo[4] = {bv.x, bv.y, bv.z, bv.w};
        float4 outv;
        float* op = &outv.x;
#pragma unroll
        for (int r = 0; r < 4; ++r)
          op[r] = mish(fmaf(fmaf(a3[r], rstd3, ms3), go[r], bo[r]));
        *(float4*)&x17lds[r15 * 132 + g * 8 + 4 * q] = outv;
      }
    }
  }

  // ---- coalesced full-line x17 dump: exactly 256 float4 stores ----
  __syncthreads();
  {
    const int cell = tid >> 5;          // 0..7
    const int off  = (tid & 31) * 4;    // 0..124
    float4 vq = *(const float4*)&x17lds[cell * 132 + off];
    *(float4*)&x17buf[(size_t)(cellbase + cell) * 128 + off] = vq;
  }
}

// ---------------------------------------------------------------------------
// Kernel 3 (unchanged r9): bfe3 twice + residual + scatter, split-precision.
// ---------------------------------------------------------------------------
__global__ __launch_bounds__(256, 3) void bfe3_mfma2_kernel(
    const float* __restrict__ x17buf, const int* __restrict__ bevcoors,
    const short* __restrict__ w3h, const short* __restrict__ w3l,
    const float* __restrict__ g3, const float* __restrict__ b3,
    float* __restrict__ out)
{
  __shared__ short x18h[4][16 * 136];
  __shared__ short x18l[4][16 * 136];

  const int tid  = threadIdx.x;
  const int lane = tid & 63;
  const int w    = tid >> 6;
  const int r15  = lane & 15;
  const int q    = lane >> 4;
  const int cell = blockIdx.x * 64 + w * 16 + r15;
  const float* xr = x17buf + (size_t)cell * 128;
  short* xh18 = &x18h[w][0];
  short* xl18 = &x18l[w][0];
  const fx4 zacc = {0.f, 0.f, 0.f, 0.f};

  short8_t xh[4], xl[4];
#pragma unroll
  for (int c = 0; c < 4; ++c) {
    const float* s = xr + 32 * c + 8 * q;
    float4 A = *(const float4*)s;
    float4 B = *(const float4*)(s + 4);
    float t[8] = {A.x, A.y, A.z, A.w, B.x, B.y, B.z, B.w};
    unsigned hu[4], lu[4];
#pragma unroll
    for (int jj = 0; jj < 4; ++jj) {
      float la, lb;
      hu[jj] = hipack(t[2 * jj], t[2 * jj + 1], la, lb);
      lu[jj] = bfpair(la, lb);
    }
    xh[c] = __builtin_bit_cast(short8_t, make_uint4(hu[0], hu[1], hu[2], hu[3]));
    xl[c] = __builtin_bit_cast(short8_t, make_uint4(lu[0], lu[1], lu[2], lu[3]));
  }

  fx4 acc[8];
#pragma unroll
  for (int f = 0; f < 8; ++f) {
    fx4 a = zacc;
#pragma unroll
    for (int c = 0; c < 4; ++c) {
      int off = (16 * f + r15) * 128 + 32 * c + 8 * q;
      short8_t Ah = *(const short8_t*)&w3h[off];
      short8_t Al = *(const short8_t*)&w3l[off];
      a = __builtin_amdgcn_mfma_f32_16x16x32_bf16(Ah, xh[c], a, 0, 0, 0);
      a = __builtin_amdgcn_mfma_f32_16x16x32_bf16(Ah, xl[c], a, 0, 0, 0);
      a = __builtin_amdgcn_mfma_f32_16x16x32_bf16(Al, xh[c], a, 0, 0, 0);
    }
    acc[f] = a;
  }
  {
    f32x2 s1v = {0.f, 0.f}, s2v = {0.f, 0.f};
#pragma unroll
    for (int f = 0; f < 8; ++f) {
      f32x2 a01 = __builtin_shufflevector(acc[f], acc[f], 0, 1);
      f32x2 a23 = __builtin_shufflevector(acc[f], acc[f], 2, 3);
      s1v = s1v + a01 + a23;
      s2v = __builtin_elementwise_fma(a01, a01, s2v);
      s2v = __builtin_elementwise_fma(a23, a23, s2v);
    }
    float s1 = s1v[0] + s1v[1], s2 = s2v[0] + s2v[1];
    s1 += __shfl_xor(s1, 16); s1 += __shfl_xor(s1, 32);
    s2 += __shfl_xor(s2, 16); s2 += __shfl_xor(s2, 32);
    float mean = s1 * (1.f / 128.f);
    float rstd = rsqrtf(fmaf(-mean, mean, s2 * (1.f / 128.f)) + EPS);
    float ms = -mean * rstd;
#pragma unroll
    for (int f = 0; f < 8; ++f) {
      float4 gv = *(const float4*)(g3 + 16 * f + 4 * q);
      float4 bv = *(const float4*)(b3 + 16 * f + 4 * q);
      float go[4] = {gv.x, gv.y, gv.z, gv.w};
      float bo[4] = {bv.x, bv.y, bv.z, bv.w};
      float o[4];
#pragma unroll
      for (int r = 0; r < 4; ++r)
        o[r] = mish(fmaf(fmaf(acc[f][r], rstd, ms), go[r], bo[r]));
      float la0, lb0, la1, lb1;
      unsigned h01 = hipack(o[0], o[1], la0, lb0);
      unsigned h23 = hipack(o[2], o[3], la1, lb1);
      *(uint2*)&xh18[r15 * 136 + 16 * f + 4 * q] = make_uint2(h01, h23);
      *(uint2*)&xl18[r15 * 136 + 16 * f + 4 * q] =
          make_uint2(bfpair(la0, lb0), bfpair(la1, lb1));
    }
  }

  short8_t yh[4], yl[4];
#pragma unroll
  for (int c = 0; c < 4; ++c) {
    yh[c] = *(short8_t*)&xh18[r15 * 136 + 32 * c + 8 * q];
    yl[c] = *(short8_t*)&xl18[r15 * 136 + 32 * c + 8 * q];
  }
#pragma unroll
  for (int f = 0; f < 8; ++f) {
    fx4 a = zacc;
#pragma unroll
    for (int c = 0; c < 4; ++c) {
      int off = (16 * f + r15) * 128 + 32 * c + 8 * q;
      short8_t Ah = *(const short8_t*)&w3h[off];
      short8_t Al = *(const short8_t*)&w3l[off];
      a = __builtin_amdgcn_mfma_f32_16x16x32_bf16(Ah, yh[c], a, 0, 0, 0);
      a = __builtin_amdgcn_mfma_f32_16x16x32_bf16(Ah, yl[c], a, 0, 0, 0);
      a = __builtin_amdgcn_mfma_f32_16x16x32_bf16(Al, yh[c], a, 0, 0, 0);
    }
    acc[f] = a;
  }
  {
    f32x2 s1v = {0.f, 0.f}, s2v = {0.f, 0.f};
#pragma unroll
    for (int f = 0; f < 8; ++f) {
      f32x2 a01 = __builtin_shufflevector(acc[f], acc[f], 0, 1);
      f32x2 a23 = __builtin_shufflevector(acc[f], acc[f], 2, 3);
      s1v = s1v + a01 + a23;
      s2v = __builtin_elementwise_fma(a01, a01, s2v);
      s2v = __builtin_elementwise_fma(a23, a23, s2v);
    }
    float s1 = s1v[0] + s1v[1], s2 = s2v[0] + s2v[1];
    s1 += __shfl_xor(s1, 16); s1 += __shfl_xor(s1, 32);
    s2 += __shfl_xor(s2, 16); s2 += __shfl_xor(s2, 32);
    float mean = s1 * (1.f / 128.f);
    float rstd = rsqrtf(fmaf(-mean, mean, s2 * (1.f / 128.f)) + EPS);
    float ms = -mean * rstd;

    int2 hw2 = *(const int2*)&bevcoors[cell * 2];   // (h, w)
    const int base = hw2.y * BEV_H + hw2.x;
#pragma unroll
    for (int f = 0; f < 8; ++f) {
      float4 gv = *(const float4*)(g3 + 16 * f + 4 * q);
      float4 bv = *(const float4*)(b3 + 16 * f + 4 * q);
      float go[4] = {gv.x, gv.y, gv.z, gv.w};
      float bo[4] = {bv.x, bv.y, bv.z, bv.w};
      float4 R = *(const float4*)(xr + 16 * f + 4 * q);
      float Ra[4] = {R.x, R.y, R.z, R.w};
#pragma unroll
      for (int r = 0; r < 4; ++r) {
        float t1 = fmaf(fmaf(acc[f][r], rstd, ms), go[r], bo[r]);
        float val = mish(t1) + Ra[r];
        out[(size_t)(16 * f + 4 * q + r) * HW + base] = val;
      }
    }
  }
}

// ---------------------------------------------------------------------------
extern "C" void kernel_launch(void* const* d_in, const int* in_sizes, int n_in,
                              void* d_out, int out_size, void* d_ws, size_t ws_size,
                              hipStream_t stream) {
  const float* voxels   = (const float*)d_in[0];
  const float* vmask    = (const float*)d_in[1];
  const int*   bevsidx  = (const int*)d_in[2];
  const int*   bevcoors = (const int*)d_in[3];
  const float* bevmask  = (const float*)d_in[4];
  const float* vfe1_W = (const float*)d_in[5];
  const float* vfe1_g = (const float*)d_in[6];
  const float* vfe1_b = (const float*)d_in[7];
  const float* vfe2_W = (const float*)d_in[8];
  const float* vfe2_g = (const float*)d_in[9];
  const float* vfe2_b = (const float*)d_in[10];
  const float* vfe3_W = (const float*)d_in[11];
  const float* vfe3_g = (const float*)d_in[12];
  const float* vfe3_b = (const float*)d_in[13];
  const float* vfe4_W = (const float*)d_in[14];
  const float* vfe4_g = (const float*)d_in[15];
  const float* vfe4_b = (const float*)d_in[16];
  const float* bfe1_W  = (const float*)d_in[17];
  const float* bfe1_g  = (const float*)d_in[18];
  const float* bfe1_b  = (const float*)d_in[19];
  const float* bfe2a_W = (const float*)d_in[20];
  const float* bfe2a_g = (const float*)d_in[21];
  const float* bfe2a_b = (const float*)d_in[22];
  const float* bfe2b_W = (const float*)d_in[23];
  const float* bfe2b_g = (const float*)d_in[24];
  const float* bfe2b_b = (const float*)d_in[25];
  const float* bfe3_W  = (const float*)d_in[26];
  const float* bfe3_g  = (const float*)d_in[27];
  const float* bfe3_b  = (const float*)d_in[28];

  unsigned short* voxelwise = (unsigned short*)d_ws;      // NV*64 bf16
  float* x17buf = (float*)(voxelwise + (size_t)NV * 64);  // NB*128 floats
  short* wbase  = (short*)(x17buf + (size_t)NB * 128);
  short* w1h  = wbase;                                // 65536
  short* w2ah = w1h + 65536;                          // 16384
  short* w2bh = w2ah + 16384;                         // 8192
  short* w3h  = w2bh + 8192;                          // 16384
  short* w3l  = w3h + 16384;                          // 16384
  float* out = (float*)d_out;

  hipMemsetAsync(d_out, 0, (size_t)out_size * sizeof(float), stream);

  pack_weights_kernel<<<(106496 + 255) / 256, 256, 0, stream>>>(
      bfe1_W, bfe2a_W, bfe2b_W, bfe3_W,
      w1h, w2ah, w2bh, w3h, w3l);

  vfe_mfma5_kernel<<<NV / 16, 256, 0, stream>>>(
      voxels, vmask,
      vfe1_W, vfe1_g, vfe1_b, vfe2_W, vfe2_g, vfe2_b,
      vfe3_W, vfe3_g, vfe3_b, vfe4_W, vfe4_g, vfe4_b,
      voxelwise);

  bfe12_mfma5_kernel<<<NB / 8, 256, SMEM_SHORTS * sizeof(short), stream>>>(
      voxelwise, bevsidx, bevmask,
      w1h, bfe1_g, bfe1_b,
      w2ah, bfe2a_g, bfe2a_b,
      w2bh, bfe2b_g, bfe2b_b,
      x17buf);

  bfe3_mfma2_kernel<<<NB / 64, 256, 0, stream>>>(
      x17buf, bevcoors, w3h, w3l, bfe3_g, bfe3_b, out);
}

// Round 11
// 426.149 us; speedup vs baseline: 1.0191x; 1.0191x over previous
//
#include <hip/hip_runtime.h>
#include <math.h>

// Problem constants (from reference setup_inputs)
constexpr int NV  = 16000;   // voxels
constexpr int P   = 32;      // points per voxel
constexpr int CIN = 10;      // input channels
constexpr int CV  = 64;      // voxel feature channels
constexpr int NB  = 16000;   // BEV cells
constexpr int BEV_H = 496, BEV_W = 432;
constexpr int HW = BEV_H * BEV_W;  // 214272
constexpr float EPS = 1e-5f;

typedef __attribute__((ext_vector_type(8))) short short8_t;  // 8 bf16 (4 VGPR)
typedef __attribute__((ext_vector_type(4))) short short4_t;  // 4 bf16
typedef __attribute__((ext_vector_type(4))) float fx4;       // MFMA C/D frag
typedef __attribute__((ext_vector_type(2))) float f32x2;     // packed f32 pair

// 8-op mish: tanh(softplus(x)) = 1 - 2/((1+e^x)^2+1)  ->  mish = x - 2x/d
__device__ __forceinline__ float mish(float x) {
  float e = __expf(fminf(x, 15.f));
  float u = 1.f + e;
  float d = fmaf(u, u, 1.f);
  float r = __builtin_amdgcn_rcpf(d);
  return fmaf(-2.f * x, r, x);
}

// RNE f32->bf16 (cold paths: weight packing)
__device__ __forceinline__ short f2bf(float f) {
  unsigned u = __builtin_bit_cast(unsigned, f);
  u += 0x7FFF + ((u >> 16) & 1);
  return (short)(u >> 16);
}
__device__ __forceinline__ float bf2f(short s) {
  unsigned u = ((unsigned)(unsigned short)s) << 16;
  return __builtin_bit_cast(float, u);
}
__device__ __forceinline__ short8_t pack8(const float* t) {
  short8_t s;
#pragma unroll
  for (int j = 0; j < 8; ++j) s[j] = f2bf(t[j]);
  return s;
}

// hot-path pack: round-half-up + v_perm pair  (low16 = bf16(a), high16 = bf16(b))
__device__ __forceinline__ unsigned bfpair(float a, float b) {
  unsigned au = __builtin_bit_cast(unsigned, a) + 0x8000u;
  unsigned bu = __builtin_bit_cast(unsigned, b) + 0x8000u;
  return __builtin_amdgcn_perm(bu, au, 0x07060302u);
}
// Dekker-style split pair: returns hi-pack, writes exact lo residuals
__device__ __forceinline__ unsigned hipack(float a, float b, float& la, float& lb) {
  unsigned ua = (__builtin_bit_cast(unsigned, a) + 0x8000u) & 0xFFFF0000u;
  unsigned ub = (__builtin_bit_cast(unsigned, b) + 0x8000u) & 0xFFFF0000u;
  la = a - __builtin_bit_cast(float, ua);
  lb = b - __builtin_bit_cast(float, ub);
  return __builtin_amdgcn_perm(ub, ua, 0x07060302u);
}

// ---------------------------------------------------------------------------
// Prologue: pack bfe weights to bf16 (hi only for bfe12; hi/lo for bfe3).
// ---------------------------------------------------------------------------
__global__ __launch_bounds__(256) void pack_weights_kernel(
    const float* __restrict__ W1, const float* __restrict__ W2a,
    const float* __restrict__ W2b, const float* __restrict__ W3,
    short* __restrict__ w1h,
    short* __restrict__ w2ah,
    short* __restrict__ w2bh,
    short* __restrict__ w3h, short* __restrict__ w3l)
{
  int i = blockIdx.x * 256 + threadIdx.x;
  if (i < 65536) {
    w1h[i] = f2bf(W1[i]);
  } else if (i < 81920) {
    int j = i - 65536;
    int g = j >> 10, o = (j >> 6) & 15, c = j & 63;
    float v = (o < 8) ? W2a[(g * 8 + o) * 64 + c] : 0.f;
    w2ah[j] = f2bf(v);
  } else if (i < 90112) {
    int k = i - 81920;
    int g = k >> 9, o = (k >> 5) & 15, c = k & 31;
    float v = (o < 8) ? W2b[(g * 8 + o) * 32 + c] : 0.f;
    w2bh[k] = f2bf(v);
  } else if (i < 106496) {
    int j = i - 90112;
    float v = W3[j];
    short h = f2bf(v);
    w3h[j] = h; w3l[j] = f2bf(v - bf2f(h));
  }
}

// ---------------------------------------------------------------------------
// VFE v5 (unchanged): bf16 voxelwise output.
// ---------------------------------------------------------------------------
__global__ __launch_bounds__(256, 4) void vfe_mfma5_kernel(
    const float* __restrict__ voxels, const float* __restrict__ vmask,
    const float* __restrict__ W1, const float* __restrict__ g1, const float* __restrict__ b1,
    const float* __restrict__ W2, const float* __restrict__ g2, const float* __restrict__ b2,
    const float* __restrict__ W3, const float* __restrict__ g3, const float* __restrict__ b3,
    const float* __restrict__ W4, const float* __restrict__ g4, const float* __restrict__ b4,
    unsigned short* __restrict__ voxelwise)
{
  __shared__ short wlds[28 * 512];
  __shared__ short actb[4][16 * 72];
  __shared__ float gblds[512];

  const int tid  = threadIdx.x;
  const int lane = tid & 63;
  const int w    = tid >> 6;
  const int p    = lane & 15;
  const int q    = lane >> 4;
  const int gw   = blockIdx.x * 4 + w;

  for (int k = tid; k < 512; k += 256) {
    int region = k >> 6, off = k & 63;
    const float* src =
        region == 0 ? g1 : region == 1 ? b1 :
        region == 2 ? g2 : region == 3 ? b2 :
        region == 4 ? g3 : region == 5 ? b3 :
        region == 6 ? g4 : b4;
    gblds[k] = src[off];
  }
  for (int s = w; s < 28; s += 4) {
    float t[8];
    if (s < 4) {
      const int f = s;
#pragma unroll
      for (int j = 0; j < 8; ++j) {
        int c = 8 * q + j;
        t[j] = (c < CIN) ? W1[(p + 16 * f) * CIN + c] : 0.f;
      }
    } else {
      const int l = (s - 4) >> 3, rem = (s - 4) & 7, ch = rem >> 2, f = rem & 3;
      const float* Wl = (l == 0) ? W2 : (l == 1) ? W3 : W4;
      const float* src = Wl + (p + 16 * f) * CV + 32 * ch + 8 * q;
#pragma unroll
      for (int j = 0; j < 8; ++j) t[j] = src[j];
    }
    *(short8_t*)&wlds[s * 512 + lane * 8] = pack8(t);
  }
  __syncthreads();

  short* mybuf = &actb[w][0];
  const fx4 zacc = {0.f, 0.f, 0.f, 0.f};
  const int srcLane = ((lane >> 2) & 3) * 16 + (((lane >> 4) & 3) << 2) + (lane & 3);

  for (int i = 0; i < 4; ++i) {
    const int v = gw * 4 + i;
    float chmax0 = 0.f, vmaxv = 0.f;

    for (int h = 0; h < 2; ++h) {
      const int ptbase = v * 32 + h * 16;
      const float m = vmask[ptbase + p];
      float x2r[16];
      float cur[16];

      // ---- layer 1 ----
      {
        const float* xrow = voxels + (size_t)(ptbase + p) * CIN;
        float t[8] = {0.f, 0.f, 0.f, 0.f, 0.f, 0.f, 0.f, 0.f};
        if (q == 0) {
          float2 a = *(const float2*)(xrow + 0);
          float2 b = *(const float2*)(xrow + 2);
          float2 c = *(const float2*)(xrow + 4);
          float2 d = *(const float2*)(xrow + 6);
          t[0] = a.x; t[1] = a.y; t[2] = b.x; t[3] = b.y;
          t[4] = c.x; t[5] = c.y; t[6] = d.x; t[7] = d.y;
        } else if (q == 1) {
          float2 a = *(const float2*)(xrow + 8);
          t[0] = a.x; t[1] = a.y;
        }
        uint4 bu = make_uint4(bfpair(t[0], t[1]), bfpair(t[2], t[3]),
                              bfpair(t[4], t[5]), bfpair(t[6], t[7]));
        short8_t bfrag = __builtin_bit_cast(short8_t, bu);
        fx4 acc[4];
#pragma unroll
        for (int f = 0; f < 4; ++f) {
          short8_t af = *(short8_t*)&wlds[f * 512 + lane * 8];
          acc[f] = __builtin_amdgcn_mfma_f32_16x16x32_bf16(af, bfrag, zacc, 0, 0, 0);
        }
        f32x2 s1v = {0.f, 0.f}, s2v = {0.f, 0.f};
#pragma unroll
        for (int f = 0; f < 4; ++f) {
          f32x2 a01 = __builtin_shufflevector(acc[f], acc[f], 0, 1);
          f32x2 a23 = __builtin_shufflevector(acc[f], acc[f], 2, 3);
          s1v = s1v + a01 + a23;
          s2v = __builtin_elementwise_fma(a01, a01, s2v);
          s2v = __builtin_elementwise_fma(a23, a23, s2v);
        }
        float s1 = s1v[0] + s1v[1], s2 = s2v[0] + s2v[1];
        s1 += __shfl_xor(s1, 16); s1 += __shfl_xor(s1, 32);
        s2 += __shfl_xor(s2, 16); s2 += __shfl_xor(s2, 32);
        float mean = s1 * (1.f / 64.f);
        float rstd = rsqrtf(fmaf(-mean, mean, s2 * (1.f / 64.f)) + EPS);
        float ms = -mean * rstd;
#pragma unroll
        for (int f = 0; f < 4; ++f) {
          float4 gv = *(const float4*)&gblds[16 * f + 4 * q];
          float4 bv = *(const float4*)&gblds[64 + 16 * f + 4 * q];
          float go[4] = {gv.x, gv.y, gv.z, gv.w};
          float bo[4] = {bv.x, bv.y, bv.z, bv.w};
          float o[4];
#pragma unroll
          for (int r = 0; r < 4; ++r)
            o[r] = mish(fmaf(fmaf(acc[f][r], rstd, ms), go[r], bo[r]));
          *(uint2*)&mybuf[p * 72 + 4 * q + 16 * f] =
              make_uint2(bfpair(o[0], o[1]), bfpair(o[2], o[3]));
        }
      }

      // ---- layers 2..4 ----
#pragma unroll 1
      for (int l = 0; l < 3; ++l) {
        short8_t bf0 = *(short8_t*)&mybuf[p * 72 + 8 * q];
        short8_t bf1 = *(short8_t*)&mybuf[p * 72 + 8 * q + 32];
        fx4 acc[4];
#pragma unroll
        for (int f = 0; f < 4; ++f) {
          short8_t a0 = *(short8_t*)&wlds[(4 + l * 8 + f) * 512 + lane * 8];
          short8_t a1 = *(short8_t*)&wlds[(4 + l * 8 + 4 + f) * 512 + lane * 8];
          fx4 a = __builtin_amdgcn_mfma_f32_16x16x32_bf16(a0, bf0, zacc, 0, 0, 0);
          acc[f] = __builtin_amdgcn_mfma_f32_16x16x32_bf16(a1, bf1, a, 0, 0, 0);
        }
        f32x2 s1v = {0.f, 0.f}, s2v = {0.f, 0.f};
#pragma unroll
        for (int f = 0; f < 4; ++f) {
          f32x2 a01 = __builtin_shufflevector(acc[f], acc[f], 0, 1);
          f32x2 a23 = __builtin_shufflevector(acc[f], acc[f], 2, 3);
          s1v = s1v + a01 + a23;
          s2v = __builtin_elementwise_fma(a01, a01, s2v);
          s2v = __builtin_elementwise_fma(a23, a23, s2v);
        }
        float s1 = s1v[0] + s1v[1], s2 = s2v[0] + s2v[1];
        s1 += __shfl_xor(s1, 16); s1 += __shfl_xor(s1, 32);
        s2 += __shfl_xor(s2, 16); s2 += __shfl_xor(s2, 32);
        float mean = s1 * (1.f / 64.f);
        float rstd = rsqrtf(fmaf(-mean, mean, s2 * (1.f / 64.f)) + EPS);
        float ms = -mean * rstd;
        const int gbbase = (l + 1) * 128;
#pragma unroll
        for (int f = 0; f < 4; ++f) {
          float4 gv = *(const float4*)&gblds[gbbase + 16 * f + 4 * q];
          float4 bv = *(const float4*)&gblds[gbbase + 64 + 16 * f + 4 * q];
          float go[4] = {gv.x, gv.y, gv.z, gv.w};
          float bo[4] = {bv.x, bv.y, bv.z, bv.w};
          if (l == 0) {
            float o[4];
#pragma unroll
            for (int r = 0; r < 4; ++r) {
              o[r] = mish(fmaf(fmaf(acc[f][r], rstd, ms), go[r], bo[r])) * m;
              x2r[f * 4 + r] = o[r];
            }
            *(uint2*)&mybuf[p * 72 + 4 * q + 16 * f] =
                make_uint2(bfpair(o[0], o[1]), bfpair(o[2], o[3]));
          } else if (l == 1) {
            float o[4];
#pragma unroll
            for (int r = 0; r < 4; ++r)
              o[r] = mish(fmaf(fmaf(acc[f][r], rstd, ms), go[r], bo[r]));
            *(uint2*)&mybuf[p * 72 + 4 * q + 16 * f] =
                make_uint2(bfpair(o[0], o[1]), bfpair(o[2], o[3]));
          } else {
#pragma unroll
            for (int r = 0; r < 4; ++r) {
              float t1 = fmaf(fmaf(acc[f][r], rstd, ms), go[r], bo[r]);
              cur[f * 4 + r] = fmaf(mish(t1), m, x2r[f * 4 + r]);
            }
          }
        }
      }

      // ---- reduce-scatter max over 16 points; lane p keeps value j=p ----
#pragma unroll
      for (int t = 0; t < 8; ++t) {
        float send = (lane & 8) ? cur[t] : cur[t + 8];
        float got  = __shfl_xor(send, 8);
        float mine = (lane & 8) ? cur[t + 8] : cur[t];
        cur[t] = fmaxf(mine, got);
      }
#pragma unroll
      for (int t = 0; t < 4; ++t) {
        float send = (lane & 4) ? cur[t] : cur[t + 4];
        float got  = __shfl_xor(send, 4);
        float mine = (lane & 4) ? cur[t + 4] : cur[t];
        cur[t] = fmaxf(mine, got);
      }
#pragma unroll
      for (int t = 0; t < 2; ++t) {
        float send = (lane & 2) ? cur[t] : cur[t + 2];
        float got  = __shfl_xor(send, 2);
        float mine = (lane & 2) ? cur[t + 2] : cur[t];
        cur[t] = fmaxf(mine, got);
      }
      {
        float send = (lane & 1) ? cur[0] : cur[1];
        float got  = __shfl_xor(send, 1);
        float mine = (lane & 1) ? cur[1] : cur[0];
        cur[0] = fmaxf(mine, got);
      }
      float hm = __shfl(cur[0], srcLane);
      if (h == 0) chmax0 = hm; else vmaxv = fmaxf(chmax0, hm);
    }
    unsigned uv = __builtin_bit_cast(unsigned, vmaxv) + 0x8000u;
    voxelwise[v * 64 + lane] = (unsigned short)(uv >> 16);
  }
}

// ---------------------------------------------------------------------------
// Kernel 2 v6: ONE-SHOT gather. Block = 4 cells x 4 waves; each wave gathers
// its one cell's full 64x64 bf16 panel in a single 16-load burst (the 4
// chunk-loads per voxel row hit one 128B line -> MSHR-merged, full line
// consumed). Barriers: 1 after gather + 1 before x17 dump. Compute phase
// (4 stages x 1 tile) is barrier-free; act/h2 wave-private. Numerics
// identical to v4/v5.
// ---------------------------------------------------------------------------
constexpr int XS_CH   = 72;                 // shorts per ch row (64 data + 8 pad)
constexpr int XS_CELL = 64 * 72 + 16;       // 4624 shorts/cell (16B aligned)
constexpr int ACT_OFF = 4 * XS_CELL;        // 18496
constexpr int ACT_WS  = 16 * 72;            // 1152 per wave
constexpr int H2_OFF  = ACT_OFF + 4 * ACT_WS;   // 23104
constexpr int H2_WS   = 16 * 40;                // 640 per wave
constexpr int X17_OFF = H2_OFF + 4 * H2_WS;     // 25664 shorts (16B aligned)
constexpr int SMEM_SHORTS = X17_OFF + 4 * 132 * 2;  // + x17lds (4*132 floats) = 26720

__device__ __forceinline__ uint2 gather_transpose(uint2 u2, int bit0, int bit1) {
  float a0 = __builtin_bit_cast(float, u2.x << 16);
  float a1 = __builtin_bit_cast(float, u2.x & 0xFFFF0000u);
  float a2 = __builtin_bit_cast(float, u2.y << 16);
  float a3 = __builtin_bit_cast(float, u2.y & 0xFFFF0000u);
  float gv0 = bit0 ? a0 : a1, gv1 = bit0 ? a2 : a3;
  float r0 = __shfl_xor(gv0, 4), r1 = __shfl_xor(gv1, 4);
  float c0 = bit0 ? r0 : a0, c1 = bit0 ? a1 : r0;
  float c2 = bit0 ? r1 : a2, c3 = bit0 ? a3 : r1;
  float h0 = bit1 ? c0 : c2, h1 = bit1 ? c1 : c3;
  float s0 = __shfl_xor(h0, 8), s1 = __shfl_xor(h1, 8);
  float d0 = bit1 ? s0 : c0, d1 = bit1 ? s1 : c1;
  float d2 = bit1 ? c2 : s0, d3 = bit1 ? c3 : s1;
  // bfpair exact here (inputs already bf16 bit patterns)
  return make_uint2(bfpair(d0, d1), bfpair(d2, d3));
}

__global__ __launch_bounds__(256, 3) void bfe12_mfma6_kernel(
    const unsigned short* __restrict__ voxelwise, const int* __restrict__ bevsidx,
    const float* __restrict__ bevmask,
    const short* __restrict__ w1h,
    const float* __restrict__ g1, const float* __restrict__ b1,
    const short* __restrict__ w2ah,
    const float* __restrict__ g2a, const float* __restrict__ b2a,
    const short* __restrict__ w2bh,
    const float* __restrict__ g2b, const float* __restrict__ b2b,
    float* __restrict__ x17buf)
{
  extern __shared__ short sm[];
  float* x17lds = (float*)&sm[X17_OFF];

  const int tid  = threadIdx.x;
  const int lane = tid & 63;
  const int w    = tid >> 6;
  const int r15  = lane & 15;
  const int q    = lane >> 4;
  const int cellbase = blockIdx.x * 4;

  const int chq   = lane & 3;
  const int v_loc = (lane >> 2) & 3;
  const int vblk  = lane >> 4;
  const int bit0  = v_loc & 1, bit1 = v_loc >> 1;

  // wave w gathers cell (cellbase + w)
  int idxr[4];
#pragma unroll
  for (int vb = 0; vb < 4; ++vb)
    idxr[vb] = bevsidx[(cellbase + w) * 64 + 16 * vb + 4 * vblk + v_loc];

  // zero h2 pad rows (4..15) — wave-private
  {
    short* zh = &sm[H2_OFF + w * H2_WS];
    for (int i = lane; i < 480; i += 64) zh[160 + i] = 0;
  }

  // ---- one-shot gather: 16 loads in flight, then transpose + stage ----
  uint2 raw[4][4];   // [vb][js]
#pragma unroll
  for (int vb = 0; vb < 4; ++vb)
#pragma unroll
    for (int js = 0; js < 4; ++js)
      raw[vb][js] = *(const uint2*)(voxelwise + (size_t)idxr[vb] * 64 +
                                    16 * js + 4 * chq);
#pragma unroll
  for (int js = 0; js < 4; ++js)
#pragma unroll
    for (int vb = 0; vb < 4; ++vb) {
      uint2 packed = gather_transpose(raw[vb][js], bit0, bit1);
      int addr = w * XS_CELL + (16 * js + 4 * chq + v_loc) * XS_CH +
                 16 * vb + 4 * vblk;
      *(uint2*)&sm[addr] = packed;
    }

  __syncthreads();   // all 4 cells' panels staged

  const fx4 zacc = {0.f, 0.f, 0.f, 0.f};
  short* acth = &sm[ACT_OFF + w * ACT_WS];
  short* h2h  = &sm[H2_OFF + w * H2_WS];

#pragma unroll 1
  for (int j = 0; j < 4; ++j) {
    const int g = 4 * j + w;

    short8_t W1f[2][4];
#pragma unroll
    for (int c = 0; c < 2; ++c)
#pragma unroll
      for (int f = 0; f < 4; ++f) {
        int off = (g * 64 + r15 + 16 * f) * 64 + 32 * c + 8 * q;
        W1f[c][f] = *(const short8_t*)&w1h[off];
      }
    short8_t W2af[2];
#pragma unroll
    for (int c = 0; c < 2; ++c) {
      int off = (g * 16 + r15) * 64 + 32 * c + 8 * q;
      W2af[c] = *(const short8_t*)&w2ah[off];
    }
    short8_t W2bf;
    {
      int off = (g * 16 + r15) * 32 + 8 * q;
      W2bf = *(const short8_t*)&w2bh[off];
    }

    // ---- single tile: 4 cells x 4 p ----
    {
      const int cl = r15 >> 2, p = r15 & 3;
      const float bm = bevmask[cellbase + cl];

      int xaddr = cl * XS_CELL + (4 * g + p) * XS_CH;
      short8_t x0 = *(short8_t*)&sm[xaddr + 8 * q];
      short8_t x1 = *(short8_t*)&sm[xaddr + 32 + 8 * q];

      fx4 acc[4];
#pragma unroll
      for (int f = 0; f < 4; ++f) {
        fx4 a = __builtin_amdgcn_mfma_f32_16x16x32_bf16(W1f[0][f], x0, zacc, 0, 0, 0);
        acc[f] = __builtin_amdgcn_mfma_f32_16x16x32_bf16(W1f[1][f], x1, a, 0, 0, 0);
      }

      f32x2 s1v = {0.f, 0.f}, s2v = {0.f, 0.f};
#pragma unroll
      for (int f = 0; f < 4; ++f) {
        f32x2 a01 = __builtin_shufflevector(acc[f], acc[f], 0, 1);
        f32x2 a23 = __builtin_shufflevector(acc[f], acc[f], 2, 3);
        s1v = s1v + a01 + a23;
        s2v = __builtin_elementwise_fma(a01, a01, s2v);
        s2v = __builtin_elementwise_fma(a23, a23, s2v);
      }
      float s1 = s1v[0] + s1v[1], s2 = s2v[0] + s2v[1];
      s1 += __shfl_xor(s1, 16); s1 += __shfl_xor(s1, 32);
      s2 += __shfl_xor(s2, 16); s2 += __shfl_xor(s2, 32);
      float mean = s1 * (1.f / 64.f);
      float rstd = rsqrtf(fmaf(-mean, mean, s2 * (1.f / 64.f)) + EPS);
      float ms = -mean * rstd;

#pragma unroll
      for (int f = 0; f < 4; ++f) {
        float4 gv = *(const float4*)(g1 + g * 64 + 16 * f + 4 * q);
        float4 bv = *(const float4*)(b1 + g * 64 + 16 * f + 4 * q);
        float go[4] = {gv.x, gv.y, gv.z, gv.w};
        float bo[4] = {bv.x, bv.y, bv.z, bv.w};
        float o[4];
#pragma unroll
        for (int r = 0; r < 4; ++r)
          o[r] = mish(fmaf(fmaf(acc[f][r], rstd, ms), go[r], bo[r])) * bm;
        *(uint2*)&acth[r15 * 72 + 16 * f + 4 * q] =
            make_uint2(bfpair(o[0], o[1]), bfpair(o[2], o[3]));
      }

      short8_t a0 = *(short8_t*)&acth[r15 * 72 + 8 * q];
      short8_t a1 = *(short8_t*)&acth[r15 * 72 + 32 + 8 * q];
      fx4 a2 = __builtin_amdgcn_mfma_f32_16x16x32_bf16(W2af[0], a0, zacc, 0, 0, 0);
      a2 = __builtin_amdgcn_mfma_f32_16x16x32_bf16(W2af[1], a1, a2, 0, 0, 0);

      float sa = a2[0] + a2[1] + a2[2] + a2[3];
      float sb = fmaf(a2[0], a2[0], fmaf(a2[1], a2[1], fmaf(a2[2], a2[2], a2[3] * a2[3])));
      sa += __shfl_xor(sa, 16); sb += __shfl_xor(sb, 16);
      if (q < 2) {
        float mean2 = sa * 0.125f;
        float rstd2 = rsqrtf(fmaf(-mean2, mean2, sb * 0.125f) + EPS);
        float ms2 = -mean2 * rstd2;
        float4 gv = *(const float4*)(g2a + g * 8 + 4 * q);
        float4 bv = *(const float4*)(b2a + g * 8 + 4 * q);
        float go[4] = {gv.x, gv.y, gv.z, gv.w};
        float bo[4] = {bv.x, bv.y, bv.z, bv.w};
        float o[4];
#pragma unroll
        for (int r = 0; r < 4; ++r)
          o[r] = mish(fmaf(fmaf(a2[r], rstd2, ms2), go[r], bo[r]));
        *(uint2*)&h2h[cl * 40 + p * 8 + 4 * q] =
            make_uint2(bfpair(o[0], o[1]), bfpair(o[2], o[3]));
      }
    }

    // ---- bfe2b: rows = 4 cells (+12 zero pad), K=32 ----
    {
      short8_t bh = *(short8_t*)&h2h[r15 * 40 + 8 * q];
      fx4 a3 = __builtin_amdgcn_mfma_f32_16x16x32_bf16(W2bf, bh, zacc, 0, 0, 0);

      float sa = a3[0] + a3[1] + a3[2] + a3[3];
      float sb = fmaf(a3[0], a3[0], fmaf(a3[1], a3[1], fmaf(a3[2], a3[2], a3[3] * a3[3])));
      sa += __shfl_xor(sa, 16); sb += __shfl_xor(sb, 16);
      if (q < 2 && r15 < 4) {
        float mean3 = sa * 0.125f;
        float rstd3 = rsqrtf(fmaf(-mean3, mean3, sb * 0.125f) + EPS);
        float ms3 = -mean3 * rstd3;
        float4 gv = *(const float4*)(g2b + g * 8 + 4 * q);
        float4 bv = *(const float4*)(b2b + g * 8 + 4 * q);
        float go[4] = {gv.x, gv.y, gv.z, gv.w};
        float bo[4] = {bv.x, bv.y, bv.z, bv.w};
        float4 outv;
        float* op = &outv.x;
#pragma unroll
        for (int r = 0; r < 4; ++r)
          op[r] = mish(fmaf(fmaf(a3[r], rstd3, ms3), go[r], bo[r]));
        *(float4*)&x17lds[r15 * 132 + g * 8 + 4 * q] = outv;
      }
    }
  }

  // ---- coalesced x17 dump: 128 float4 stores (4 cells x 128 floats) ----
  __syncthreads();
  if (tid < 128) {
    const int cell = tid >> 5;          // 0..3
    const int off  = (tid & 31) * 4;    // 0..124
    float4 vq = *(const float4*)&x17lds[cell * 132 + off];
    *(float4*)&x17buf[(size_t)(cellbase + cell) * 128 + off] = vq;
  }
}

// ---------------------------------------------------------------------------
// Kernel 3 (unchanged): bfe3 twice + residual + scatter, split-precision.
// ---------------------------------------------------------------------------
__global__ __launch_bounds__(256, 3) void bfe3_mfma2_kernel(
    const float* __restrict__ x17buf, const int* __restrict__ bevcoors,
    const short* __restrict__ w3h, const short* __restrict__ w3l,
    const float* __restrict__ g3, const float* __restrict__ b3,
    float* __restrict__ out)
{
  __shared__ short x18h[4][16 * 136];
  __shared__ short x18l[4][16 * 136];

  const int tid  = threadIdx.x;
  const int lane = tid & 63;
  const int w    = tid >> 6;
  const int r15  = lane & 15;
  const int q    = lane >> 4;
  const int cell = blockIdx.x * 64 + w * 16 + r15;
  const float* xr = x17buf + (size_t)cell * 128;
  short* xh18 = &x18h[w][0];
  short* xl18 = &x18l[w][0];
  const fx4 zacc = {0.f, 0.f, 0.f, 0.f};

  short8_t xh[4], xl[4];
#pragma unroll
  for (int c = 0; c < 4; ++c) {
    const float* s = xr + 32 * c + 8 * q;
    float4 A = *(const float4*)s;
    float4 B = *(const float4*)(s + 4);
    float t[8] = {A.x, A.y, A.z, A.w, B.x, B.y, B.z, B.w};
    unsigned hu[4], lu[4];
#pragma unroll
    for (int jj = 0; jj < 4; ++jj) {
      float la, lb;
      hu[jj] = hipack(t[2 * jj], t[2 * jj + 1], la, lb);
      lu[jj] = bfpair(la, lb);
    }
    xh[c] = __builtin_bit_cast(short8_t, make_uint4(hu[0], hu[1], hu[2], hu[3]));
    xl[c] = __builtin_bit_cast(short8_t, make_uint4(lu[0], lu[1], lu[2], lu[3]));
  }

  fx4 acc[8];
#pragma unroll
  for (int f = 0; f < 8; ++f) {
    fx4 a = zacc;
#pragma unroll
    for (int c = 0; c < 4; ++c) {
      int off = (16 * f + r15) * 128 + 32 * c + 8 * q;
      short8_t Ah = *(const short8_t*)&w3h[off];
      short8_t Al = *(const short8_t*)&w3l[off];
      a = __builtin_amdgcn_mfma_f32_16x16x32_bf16(Ah, xh[c], a, 0, 0, 0);
      a = __builtin_amdgcn_mfma_f32_16x16x32_bf16(Ah, xl[c], a, 0, 0, 0);
      a = __builtin_amdgcn_mfma_f32_16x16x32_bf16(Al, xh[c], a, 0, 0, 0);
    }
    acc[f] = a;
  }
  {
    f32x2 s1v = {0.f, 0.f}, s2v = {0.f, 0.f};
#pragma unroll
    for (int f = 0; f < 8; ++f) {
      f32x2 a01 = __builtin_shufflevector(acc[f], acc[f], 0, 1);
      f32x2 a23 = __builtin_shufflevector(acc[f], acc[f], 2, 3);
      s1v = s1v + a01 + a23;
      s2v = __builtin_elementwise_fma(a01, a01, s2v);
      s2v = __builtin_elementwise_fma(a23, a23, s2v);
    }
    float s1 = s1v[0] + s1v[1], s2 = s2v[0] + s2v[1];
    s1 += __shfl_xor(s1, 16); s1 += __shfl_xor(s1, 32);
    s2 += __shfl_xor(s2, 16); s2 += __shfl_xor(s2, 32);
    float mean = s1 * (1.f / 128.f);
    float rstd = rsqrtf(fmaf(-mean, mean, s2 * (1.f / 128.f)) + EPS);
    float ms = -mean * rstd;
#pragma unroll
    for (int f = 0; f < 8; ++f) {
      float4 gv = *(const float4*)(g3 + 16 * f + 4 * q);
      float4 bv = *(const float4*)(b3 + 16 * f + 4 * q);
      float go[4] = {gv.x, gv.y, gv.z, gv.w};
      float bo[4] = {bv.x, bv.y, bv.z, bv.w};
      float o[4];
#pragma unroll
      for (int r = 0; r < 4; ++r)
        o[r] = mish(fmaf(fmaf(acc[f][r], rstd, ms), go[r], bo[r]));
      float la0, lb0, la1, lb1;
      unsigned h01 = hipack(o[0], o[1], la0, lb0);
      unsigned h23 = hipack(o[2], o[3], la1, lb1);
      *(uint2*)&xh18[r15 * 136 + 16 * f + 4 * q] = make_uint2(h01, h23);
      *(uint2*)&xl18[r15 * 136 + 16 * f + 4 * q] =
          make_uint2(bfpair(la0, lb0), bfpair(la1, lb1));
    }
  }

  short8_t yh[4], yl[4];
#pragma unroll
  for (int c = 0; c < 4; ++c) {
    yh[c] = *(short8_t*)&xh18[r15 * 136 + 32 * c + 8 * q];
    yl[c] = *(short8_t*)&xl18[r15 * 136 + 32 * c + 8 * q];
  }
#pragma unroll
  for (int f = 0; f < 8; ++f) {
    fx4 a = zacc;
#pragma unroll
    for (int c = 0; c < 4; ++c) {
      int off = (16 * f + r15) * 128 + 32 * c + 8 * q;
      short8_t Ah = *(const short8_t*)&w3h[off];
      short8_t Al = *(const short8_t*)&w3l[off];
      a = __builtin_amdgcn_mfma_f32_16x16x32_bf16(Ah, yh[c], a, 0, 0, 0);
      a = __builtin_amdgcn_mfma_f32_16x16x32_bf16(Ah, yl[c], a, 0, 0, 0);
      a = __builtin_amdgcn_mfma_f32_16x16x32_bf16(Al, yh[c], a, 0, 0, 0);
    }
    acc[f] = a;
  }
  {
    f32x2 s1v = {0.f, 0.f}, s2v = {0.f, 0.f};
#pragma unroll
    for (int f = 0; f < 8; ++f) {
      f32x2 a01 = __builtin_shufflevector(acc[f], acc[f], 0, 1);
      f32x2 a23 = __builtin_shufflevector(acc[f], acc[f], 2, 3);
      s1v = s1v + a01 + a23;
      s2v = __builtin_elementwise_fma(a01, a01, s2v);
      s2v = __builtin_elementwise_fma(a23, a23, s2v);
    }
    float s1 = s1v[0] + s1v[1], s2 = s2v[0] + s2v[1];
    s1 += __shfl_xor(s1, 16); s1 += __shfl_xor(s1, 32);
    s2 += __shfl_xor(s2, 16); s2 += __shfl_xor(s2, 32);
    float mean = s1 * (1.f / 128.f);
    float rstd = rsqrtf(fmaf(-mean, mean, s2 * (1.f / 128.f)) + EPS);
    float ms = -mean * rstd;

    int2 hw2 = *(const int2*)&bevcoors[cell * 2];   // (h, w)
    const int base = hw2.y * BEV_H + hw2.x;
#pragma unroll
    for (int f = 0; f < 8; ++f) {
      float4 gv = *(const float4*)(g3 + 16 * f + 4 * q);
      float4 bv = *(const float4*)(b3 + 16 * f + 4 * q);
      float go[4] = {gv.x, gv.y, gv.z, gv.w};
      float bo[4] = {bv.x, bv.y, bv.z, bv.w};
      float4 R = *(const float4*)(xr + 16 * f + 4 * q);
      float Ra[4] = {R.x, R.y, R.z, R.w};
#pragma unroll
      for (int r = 0; r < 4; ++r) {
        float t1 = fmaf(fmaf(acc[f][r], rstd, ms), go[r], bo[r]);
        float val = mish(t1) + Ra[r];
        out[(size_t)(16 * f + 4 * q + r) * HW + base] = val;
      }
    }
  }
}

// ---------------------------------------------------------------------------
extern "C" void kernel_launch(void* const* d_in, const int* in_sizes, int n_in,
                              void* d_out, int out_size, void* d_ws, size_t ws_size,
                              hipStream_t stream) {
  const float* voxels   = (const float*)d_in[0];
  const float* vmask    = (const float*)d_in[1];
  const int*   bevsidx  = (const int*)d_in[2];
  const int*   bevcoors = (const int*)d_in[3];
  const float* bevmask  = (const float*)d_in[4];
  const float* vfe1_W = (const float*)d_in[5];
  const float* vfe1_g = (const float*)d_in[6];
  const float* vfe1_b = (const float*)d_in[7];
  const float* vfe2_W = (const float*)d_in[8];
  const float* vfe2_g = (const float*)d_in[9];
  const float* vfe2_b = (const float*)d_in[10];
  const float* vfe3_W = (const float*)d_in[11];
  const float* vfe3_g = (const float*)d_in[12];
  const float* vfe3_b = (const float*)d_in[13];
  const float* vfe4_W = (const float*)d_in[14];
  const float* vfe4_g = (const float*)d_in[15];
  const float* vfe4_b = (const float*)d_in[16];
  const float* bfe1_W  = (const float*)d_in[17];
  const float* bfe1_g  = (const float*)d_in[18];
  const float* bfe1_b  = (const float*)d_in[19];
  const float* bfe2a_W = (const float*)d_in[20];
  const float* bfe2a_g = (const float*)d_in[21];
  const float* bfe2a_b = (const float*)d_in[22];
  const float* bfe2b_W = (const float*)d_in[23];
  const float* bfe2b_g = (const float*)d_in[24];
  const float* bfe2b_b = (const float*)d_in[25];
  const float* bfe3_W  = (const float*)d_in[26];
  const float* bfe3_g  = (const float*)d_in[27];
  const float* bfe3_b  = (const float*)d_in[28];

  unsigned short* voxelwise = (unsigned short*)d_ws;      // NV*64 bf16
  float* x17buf = (float*)(voxelwise + (size_t)NV * 64);  // NB*128 floats
  short* wbase  = (short*)(x17buf + (size_t)NB * 128);
  short* w1h  = wbase;                                // 65536
  short* w2ah = w1h + 65536;                          // 16384
  short* w2bh = w2ah + 16384;                         // 8192
  short* w3h  = w2bh + 8192;                          // 16384
  short* w3l  = w3h + 16384;                          // 16384
  float* out = (float*)d_out;

  hipMemsetAsync(d_out, 0, (size_t)out_size * sizeof(float), stream);

  pack_weights_kernel<<<(106496 + 255) / 256, 256, 0, stream>>>(
      bfe1_W, bfe2a_W, bfe2b_W, bfe3_W,
      w1h, w2ah, w2bh, w3h, w3l);

  vfe_mfma5_kernel<<<NV / 16, 256, 0, stream>>>(
      voxels, vmask,
      vfe1_W, vfe1_g, vfe1_b, vfe2_W, vfe2_g, vfe2_b,
      vfe3_W, vfe3_g, vfe3_b, vfe4_W, vfe4_g, vfe4_b,
      voxelwise);

  bfe12_mfma6_kernel<<<NB / 4, 256, SMEM_SHORTS * sizeof(short), stream>>>(
      voxelwise, bevsidx, bevmask,
      w1h, bfe1_g, bfe1_b,
      w2ah, bfe2a_g, bfe2a_b,
      w2bh, bfe2b_g, bfe2b_b,
      x17buf);

  bfe3_mfma2_kernel<<<NB / 64, 256, 0, stream>>>(
      x17buf, bevcoors, w3h, w3l, bfe3_g, bfe3_b, out);
}